// Round 1
// baseline (458.825 us; speedup 1.0000x reference)
//
#include <hip/hip_runtime.h>
#include <hip/hip_bf16.h>

// Problem: FeatureAdaption (DCNv1). B=4, CIN=COUT=128, H=W=128, K=3, G=4, CG=32.
// in: x[4,128,128,128] f32, w_off[72,128] f32, b_off[72] f32, w_def[128,128,3,3] f32
// out: relu(deform_conv(x, offset_conv(x))) f32 [4,128,128,128]
//
// ws layout (floats):
//   [0,        9216)      wT_off [128 c][72 o]
//   [9216,     156672)    wT_def [9 kk][128 c][128 o]
//   [156672,   4875264)   offs   [4 b][72 o][16384 pix]   (~19.5 MB total)

#define HW 16384   // H*W
#define NPIX 64    // pixels per block (half a row)

// ---------------- kernel 0: weight transposes ----------------
__global__ __launch_bounds__(256) void transpose_w(
    const float* __restrict__ w_off, const float* __restrict__ w_def,
    float* __restrict__ wT_off, float* __restrict__ wT_def) {
  int idx = blockIdx.x * 256 + threadIdx.x;
  int stride = gridDim.x * 256;
  // w_off [72 o][128 c] -> wT_off [128 c][72 o]
  for (int i = idx; i < 72 * 128; i += stride) {
    int o = i / 128, c = i % 128;
    wT_off[c * 72 + o] = w_off[i];
  }
  // w_def [128 o][128 c][9 kk] -> wT_def [9 kk][128 c][128 o]
  for (int i = idx; i < 128 * 128 * 9; i += stride) {
    int o = i / 1152;
    int r = i - o * 1152;
    int c = r / 9;
    int kk = r - c * 9;
    wT_def[(kk * 128 + c) * 128 + o] = w_def[i];
  }
}

// ---------------- kernel 1: 1x1 offset conv ----------------
// grid 1024: tile = 64 consecutive pixels; block 256 = 64 pix x 4 o-chunks(18)
__global__ __launch_bounds__(256) void offset_conv(
    const float* __restrict__ x, const float* __restrict__ wT_off,
    const float* __restrict__ b_off, float* __restrict__ offs) {
  int tid = threadIdx.x;
  int lane = tid & 63;
  int oc = __builtin_amdgcn_readfirstlane(tid >> 6);  // wave-uniform o-chunk
  int o0 = oc * 18;
  int tile = blockIdx.x;
  int b = tile >> 8;                       // 256 tiles per image
  int pix = ((tile & 255) << 6) + lane;    // 0..16383
  const float* xp = x + (size_t)b * 128 * HW + pix;

  float acc[18];
#pragma unroll
  for (int i = 0; i < 18; i++) acc[i] = b_off[o0 + i];  // uniform -> s_load

#pragma unroll 4
  for (int c = 0; c < 128; c++) {
    float xv = xp[(size_t)c * HW];                      // coalesced
    const float* wr = wT_off + c * 72 + o0;             // uniform -> s_load
#pragma unroll
    for (int i = 0; i < 18; i++) acc[i] = fmaf(xv, wr[i], acc[i]);
  }
  float* op = offs + (size_t)b * 72 * HW + pix;
#pragma unroll
  for (int i = 0; i < 18; i++) op[(size_t)(o0 + i) * HW] = acc[i];
}

// ---------------- kernel 2: fused bilinear sample + 3x3 conv + relu ----------------
// grid 1024: blk -> (b, h, w0 in {0,64}); block 256 threads.
// Phases per kk: (a) 256 bilinear records -> LDS, (b) stage val[128c][64pix] -> LDS,
// (c) accumulate acc[32 o] per thread with scalar weight loads.
__global__ __launch_bounds__(256) void deform_conv(
    const float* __restrict__ x, const float* __restrict__ wT_def,
    const float* __restrict__ offs, float* __restrict__ out) {
  __shared__ int   bil_a[4][256];   // clamped corner addr (y*128+x) per (g,lane)
  __shared__ float bil_w[4][256];   // bilinear weight with validity folded in
  __shared__ float val_lds[128 * NPIX];

  int tid = threadIdx.x;
  int lane = tid & 63;
  int hi = tid >> 6;                          // 0..3: g in phase(a), c-phase in (b), o-group in (c)
  int blk = blockIdx.x;
  int b = blk >> 8;
  int rem = blk & 255;
  int h = rem >> 1;
  int w0 = (rem & 1) * NPIX;
  int hw = h * 128 + w0 + lane;

  const float* xb_base = x + (size_t)b * 128 * HW;
  int o0 = __builtin_amdgcn_readfirstlane(hi) * 32;

  float acc[32];
#pragma unroll
  for (int i = 0; i < 32; i++) acc[i] = 0.f;

  for (int kk = 0; kk < 9; kk++) {
    __syncthreads();
    // ---- (a) bilinear records: one per thread, rec = g*64 + lane ----
    {
      int g = hi;
      int rec = g * 64 + lane;
      float dy = offs[((size_t)b * 72 + g * 18 + kk * 2 + 0) * HW + hw];
      float dx = offs[((size_t)b * 72 + g * 18 + kk * 2 + 1) * HW + hw];
      float py = (float)h + (float)(kk / 3 - 1) + dy;
      float px = (float)(w0 + lane) + (float)(kk % 3 - 1) + dx;
      float y0f = floorf(py), x0f = floorf(px);
      int y0 = (int)y0f, x0 = (int)x0f;
      float wy1 = py - y0f, wx1 = px - x0f;
      float wy0 = 1.f - wy1, wx0 = 1.f - wx1;
      int y1 = y0 + 1, x1 = x0 + 1;
      float fy0 = (y0 >= 0 && y0 < 128) ? 1.f : 0.f;
      float fy1 = (y1 >= 0 && y1 < 128) ? 1.f : 0.f;
      float fx0 = (x0 >= 0 && x0 < 128) ? 1.f : 0.f;
      float fx1 = (x1 >= 0 && x1 < 128) ? 1.f : 0.f;
      int y0c = min(max(y0, 0), 127), y1c = min(max(y1, 0), 127);
      int x0c = min(max(x0, 0), 127), x1c = min(max(x1, 0), 127);
      bil_a[0][rec] = y0c * 128 + x0c;  bil_w[0][rec] = wy0 * wx0 * fy0 * fx0;
      bil_a[1][rec] = y0c * 128 + x1c;  bil_w[1][rec] = wy0 * wx1 * fy0 * fx1;
      bil_a[2][rec] = y1c * 128 + x0c;  bil_w[2][rec] = wy1 * wx0 * fy1 * fx0;
      bil_a[3][rec] = y1c * 128 + x1c;  bil_w[3][rec] = wy1 * wx1 * fy1 * fx1;
    }
    __syncthreads();
    // ---- (b) stage val: 32 samples/thread, c = hi + 4*j, pix = lane ----
#pragma unroll 4
    for (int j = 0; j < 32; j++) {
      int c = hi + 4 * j;
      int g = c >> 5;
      int rec = g * 64 + lane;
      const float* xb = xb_base + (size_t)c * HW;
      float v = bil_w[0][rec] * xb[bil_a[0][rec]]
              + bil_w[1][rec] * xb[bil_a[1][rec]]
              + bil_w[2][rec] * xb[bil_a[2][rec]]
              + bil_w[3][rec] * xb[bil_a[3][rec]];
      val_lds[c * NPIX + lane] = v;
    }
    __syncthreads();
    // ---- (c) accumulate: per c, 1 ds_read + 32 scalar w-loads + 32 fma ----
    const float* wkk = wT_def + kk * 16384 + o0;
#pragma unroll 2
    for (int c = 0; c < 128; c++) {
      float xv = val_lds[c * NPIX + lane];
      const float* wr = wkk + c * 128;                  // wave-uniform -> s_load_dwordx8
#pragma unroll
      for (int i = 0; i < 32; i++) acc[i] = fmaf(xv, wr[i], acc[i]);
    }
  }

  float* op = out + ((size_t)b * 128 + o0) * HW + h * 128 + w0 + lane;
#pragma unroll
  for (int i = 0; i < 32; i++) op[(size_t)i * HW] = fmaxf(acc[i], 0.f);
}

extern "C" void kernel_launch(void* const* d_in, const int* in_sizes, int n_in,
                              void* d_out, int out_size, void* d_ws, size_t ws_size,
                              hipStream_t stream) {
  const float* x     = (const float*)d_in[0];
  const float* w_off = (const float*)d_in[1];
  const float* b_off = (const float*)d_in[2];
  const float* w_def = (const float*)d_in[3];
  float* out = (float*)d_out;

  float* ws = (float*)d_ws;
  float* wT_off = ws;                       // 9216 f
  float* wT_def = ws + 9216;                // 147456 f
  float* offs   = ws + 9216 + 147456;       // 4718592 f  (~19.5 MB total)

  hipLaunchKernelGGL(transpose_w, dim3(128), dim3(256), 0, stream, w_off, w_def, wT_off, wT_def);
  hipLaunchKernelGGL(offset_conv, dim3(1024), dim3(256), 0, stream, x, wT_off, b_off, offs);
  hipLaunchKernelGGL(deform_conv, dim3(1024), dim3(256), 0, stream, x, wT_def, offs, out);
}

// Round 2
// 337.122 us; speedup vs baseline: 1.3610x; 1.3610x over previous
//
#include <hip/hip_runtime.h>
#include <hip/hip_bf16.h>

// FeatureAdaption (DCNv1). B=4, CIN=COUT=128, H=W=128, K=3, G=4, CG=32.
// Round 2: deform conv as bf16-MFMA implicit GEMM (M=128 o, N=128 pix/row-block,
// K=1152), gather with paired float2 corner loads, XCD band swizzle.
//
// ws layout (floats):
//   [0,      9216)    wT_off [128 c][72 o]                 fp32
//   [9216,  82944)    wfrag  [9 kk][4 s][8 ot][64 l][8 j]  bf16 (147456 shorts)
//   [82944, 4801536)  offs   [4 b][72 o][16384 pix]        fp32

#define HW 16384

typedef short short8 __attribute__((ext_vector_type(8)));
typedef float floatx4 __attribute__((ext_vector_type(4)));
struct F2 { float x, y; };   // align 4: hardware allows 4B-aligned dwordx2

static __device__ __forceinline__ short bf16bits(float v) {
  __hip_bfloat16 hb = __float2bfloat16(v);
  return __builtin_bit_cast(short, hb);
}

// ---------------- kernel 0: weight prep ----------------
// wT_off fp32 transpose; wfrag = w_def in MFMA A-fragment order, bf16:
//   element (kk,s,ot,l,j): o = ot*16 + (l&15), c = s*32 + (l>>4)*8 + j
__global__ __launch_bounds__(256) void prep_w(
    const float* __restrict__ w_off, const float* __restrict__ w_def,
    float* __restrict__ wT_off, short* __restrict__ wfrag) {
  int idx = blockIdx.x * 256 + threadIdx.x;
  int stride = gridDim.x * 256;
  for (int i = idx; i < 72 * 128; i += stride) {
    int o = i / 128, c = i - o * 128;
    wT_off[c * 72 + o] = w_off[i];
  }
  for (int i = idx; i < 147456; i += stride) {
    int j = i & 7, l = (i >> 3) & 63, ot = (i >> 9) & 7, s = (i >> 12) & 3, kk = i >> 14;
    int o = ot * 16 + (l & 15);
    int c = s * 32 + ((l >> 4) << 3) + j;
    wfrag[i] = bf16bits(w_def[(o * 128 + c) * 9 + kk]);
  }
}

// ---------------- kernel 1: 1x1 offset conv (fp32) ----------------
__global__ __launch_bounds__(256) void offset_conv(
    const float* __restrict__ x, const float* __restrict__ wT_off,
    const float* __restrict__ b_off, float* __restrict__ offs) {
  int tid = threadIdx.x;
  int lane = tid & 63;
  int oc = __builtin_amdgcn_readfirstlane(tid >> 6);
  int o0 = oc * 18;
  int tile = blockIdx.x;
  int b = tile >> 8;
  int pix = ((tile & 255) << 6) + lane;
  const float* xp = x + (size_t)b * 128 * HW + pix;

  float acc[18];
#pragma unroll
  for (int i = 0; i < 18; i++) acc[i] = b_off[o0 + i];
#pragma unroll 4
  for (int c = 0; c < 128; c++) {
    float xv = xp[(size_t)c * HW];
    const float* wr = wT_off + c * 72 + o0;
#pragma unroll
    for (int i = 0; i < 18; i++) acc[i] = fmaf(xv, wr[i], acc[i]);
  }
  float* op = offs + (size_t)b * 72 * HW + pix;
#pragma unroll
  for (int i = 0; i < 18; i++) op[(size_t)(o0 + i) * HW] = acc[i];
}

// ---------------- kernel 2: deform conv, bf16 MFMA ----------------
// grid 512: one block per (b, h) row; block 256 = 4 waves.
// Per kk: (a) 512 bilinear records (4g x 128pix) -> LDS
//         (b) gather: paired float2 corner loads, pack bf16 -> B-frag LDS
//         (c) 4 waves x 64 MFMA 16x16x32_bf16 (wave wv: o in [wv*32,wv*32+32))
__global__ __launch_bounds__(256, 3) void deform_conv(
    const float* __restrict__ x, const short* __restrict__ wfrag,
    const float* __restrict__ offs, float* __restrict__ out) {
  __shared__ int rec_a0[512], rec_a1[512];
  __shared__ float rec_wy0[512], rec_wy1[512], rec_wA[512], rec_wB[512];
  __shared__ __align__(16) short bfrag[16384];   // [s4][pt8][lane64][j8] bf16

  int tid = threadIdx.x;
  int lane = tid & 63;
  int wv = tid >> 6;          // wave 0..3
  int p = tid & 127;          // pixel in row (record/gather phases)
  int thalf = tid >> 7;       // 0/1

  // XCD band swizzle: each XCD gets 64 consecutive rows of one image
  int i = blockIdx.x;                 // 0..511
  int L = (i & 7) * 64 + (i >> 3);
  int b = L >> 7, h = L & 127;

  const float* xb_base = x + (size_t)b * 128 * HW;

  floatx4 acc[2][8];
#pragma unroll
  for (int ot = 0; ot < 2; ot++)
#pragma unroll
    for (int pt = 0; pt < 8; pt++) acc[ot][pt] = (floatx4)0.f;

  for (int kk = 0; kk < 9; kk++) {
    __syncthreads();   // protect rec+bfrag from previous iteration's readers
    // ---- (a) bilinear records: thread -> (g = thalf, thalf+2), pix = p ----
#pragma unroll
    for (int gg = 0; gg < 2; gg++) {
      int g = thalf + 2 * gg;
      const float* offp = offs + ((size_t)b * 72 + g * 18 + kk * 2) * HW + h * 128 + p;
      float dy = offp[0];
      float dx = offp[HW];
      float py = (float)h + (float)(kk / 3 - 1) + dy;
      float px = (float)p + (float)(kk % 3 - 1) + dx;
      float y0f = floorf(py), x0f = floorf(px);
      int y0 = (int)y0f, x0 = (int)x0f;
      float wy1 = py - y0f, wx1 = px - x0f;
      float wy0 = 1.f - wy1, wx0 = 1.f - wx1;
      int y1 = y0 + 1, x1 = x0 + 1;
      // paired-load column weights: load float2 at xb; remap clamp/validity
      int xb = min(max(x0, 0), 126);
      float fx0 = (x0 >= 0 && x0 <= 127) ? 1.f : 0.f;
      float fx1 = (x1 >= 0 && x1 <= 127) ? 1.f : 0.f;
      float wAv = (x0 == xb ? wx0 * fx0 : 0.f) + (x1 == xb ? wx1 * fx1 : 0.f);
      float wBv = (x0 == xb + 1 ? wx0 * fx0 : 0.f) + (x1 == xb + 1 ? wx1 * fx1 : 0.f);
      float fy0 = (y0 >= 0 && y0 <= 127) ? 1.f : 0.f;
      float fy1 = (y1 >= 0 && y1 <= 127) ? 1.f : 0.f;
      int y0c = min(max(y0, 0), 127), y1c = min(max(y1, 0), 127);
      int r = (g << 7) | p;
      rec_a0[r] = y0c * 128 + xb;
      rec_a1[r] = y1c * 128 + xb;
      rec_wy0[r] = wy0 * fy0;
      rec_wy1[r] = wy1 * fy1;
      rec_wA[r] = wAv;
      rec_wB[r] = wBv;
    }
    __syncthreads();
    // ---- (b) gather + bf16 pack into B-fragment layout ----
    // thread: pix = p, octets o8 = thalf + 2*oo (8 c each); s = o8>>2 = group
#pragma unroll
    for (int oo = 0; oo < 8; oo++) {
      int o8 = thalf + 2 * oo;
      int g = o8 >> 2;
      int r = (g << 7) | p;
      int a0 = rec_a0[r], a1 = rec_a1[r];
      float wy0f = rec_wy0[r], wy1f = rec_wy1[r];
      float wAv = rec_wA[r], wBv = rec_wB[r];
      const float* xc = xb_base + (size_t)(o8 * 8) * HW;
      short8 pk;
#pragma unroll
      for (int j = 0; j < 8; j++) {
        F2 q0 = *(const F2*)(xc + (size_t)j * HW + a0);
        F2 q1 = *(const F2*)(xc + (size_t)j * HW + a1);
        float v = wy0f * fmaf(wAv, q0.x, wBv * q0.y)
                + wy1f * fmaf(wAv, q1.x, wBv * q1.y);
        pk[j] = bf16bits(v);
      }
      int idx = ((g * 8 + (p >> 4)) * 64 + (o8 & 3) * 16 + (p & 15));
      *(short8*)(bfrag + idx * 8) = pk;   // ds_write_b128
    }
    __syncthreads();
    // ---- (c) MFMA: wave wv -> o tiles {2wv, 2wv+1} x 8 pix tiles ----
    const short* wk = wfrag + kk * 16384;
#pragma unroll
    for (int s = 0; s < 4; s++) {
      short8 av0 = *(const short8*)(wk + ((s * 8 + 2 * wv) * 64 + lane) * 8);
      short8 av1 = *(const short8*)(wk + ((s * 8 + 2 * wv + 1) * 64 + lane) * 8);
#pragma unroll
      for (int pt = 0; pt < 8; pt++) {
        short8 bv = *(const short8*)(bfrag + ((s * 8 + pt) * 64 + lane) * 8);
        acc[0][pt] = __builtin_amdgcn_mfma_f32_16x16x32_bf16(av0, bv, acc[0][pt], 0, 0, 0);
        acc[1][pt] = __builtin_amdgcn_mfma_f32_16x16x32_bf16(av1, bv, acc[1][pt], 0, 0, 0);
      }
    }
  }

  // ---- epilogue: C/D layout col=lane&15 (pix), row=(lane>>4)*4+reg (o) ----
  float* ob = out + (size_t)(b * 128 + wv * 32) * HW + h * 128;
  int quad = lane >> 4;
  int pcol = lane & 15;
#pragma unroll
  for (int ot = 0; ot < 2; ot++)
#pragma unroll
    for (int pt = 0; pt < 8; pt++) {
      floatx4 f = acc[ot][pt];
#pragma unroll
      for (int reg = 0; reg < 4; reg++) {
        int o = ot * 16 + quad * 4 + reg;
        int pp = pt * 16 + pcol;
        ob[(size_t)o * HW + pp] = fmaxf(f[reg], 0.f);
      }
    }
}

extern "C" void kernel_launch(void* const* d_in, const int* in_sizes, int n_in,
                              void* d_out, int out_size, void* d_ws, size_t ws_size,
                              hipStream_t stream) {
  const float* x     = (const float*)d_in[0];
  const float* w_off = (const float*)d_in[1];
  const float* b_off = (const float*)d_in[2];
  const float* w_def = (const float*)d_in[3];
  float* out = (float*)d_out;

  float* ws = (float*)d_ws;
  float* wT_off = ws;                         // 9216 f
  short* wfrag  = (short*)(ws + 9216);        // 147456 bf16 (73728 f)
  float* offs   = ws + 9216 + 73728;          // 4718592 f

  hipLaunchKernelGGL(prep_w, dim3(288), dim3(256), 0, stream, w_off, w_def, wT_off, wfrag);
  hipLaunchKernelGGL(offset_conv, dim3(1024), dim3(256), 0, stream, x, wT_off, b_off, offs);
  hipLaunchKernelGGL(deform_conv, dim3(512), dim3(256), 0, stream, x, wfrag, offs, out);
}

// Round 4
// 164.105 us; speedup vs baseline: 2.7959x; 2.0543x over previous
//
#include <hip/hip_runtime.h>
#include <hip/hip_bf16.h>
#include <hip/hip_fp16.h>

// FeatureAdaption (DCNv1). B=4, CIN=COUT=128, H=W=128, K=3, G=4, CG=32.
// Round 4 (= round-3 plan + pkrtz type fix): LDS-staged bilinear gather
// (packed f16), MFMA everywhere.
//   deform: per block = one (b,h) row. For each 16-ch sub-chunk: stage
//   7 rows x 16 ch of x into LDS as f16 channel-quads; gather via ds_read_b64
//   + v_pk_fma_f16; write MFMA B-frags (K=16); mfma_f32_16x16x16f16.
//   offset conv: f16 MFMA, M=80(72 valid), K=128; output packed half2 (dy,dx).
//
// ws layout (bytes):
//   [0,      294912)   wdef  A-frags f16 [kk9][sc8][ot8][lane64][j4]
//   [294912, 315392)   woff  A-frags f16 [ks4][mt5][lane64][j8] (rows>=72 zero)
//   [315392, 9752576)  offs2 u32 [b4][36 o-pairs][16384]  (half2 dy,dx)

#define HW 16384

typedef _Float16 h2 __attribute__((ext_vector_type(2)));
typedef _Float16 h4 __attribute__((ext_vector_type(4)));
typedef _Float16 h8 __attribute__((ext_vector_type(8)));
typedef float floatx4 __attribute__((ext_vector_type(4)));

static __device__ __forceinline__ unsigned pkrtz(float a, float b) {
  auto h = __builtin_amdgcn_cvt_pkrtz(a, b);   // __fp16 ext_vector(2)
  return __builtin_bit_cast(unsigned, h);
}
static __device__ __forceinline__ h2 u2h2(unsigned u) { return __builtin_bit_cast(h2, u); }
static __device__ __forceinline__ unsigned h2u(h2 h) { return __builtin_bit_cast(unsigned, h); }

// ---------------- kernel 0: weight prep ----------------
__global__ __launch_bounds__(256) void prep_w(
    const float* __restrict__ w_off, const float* __restrict__ w_def,
    _Float16* __restrict__ woff, _Float16* __restrict__ wdef) {
  int idx = blockIdx.x * 256 + threadIdx.x;
  int stride = gridDim.x * 256;
  // wdef A-frag (16x16x16): o = ot*16+(lane&15), c = sc*16+(lane>>4)*4+j
  for (int i = idx; i < 147456; i += stride) {
    int j = i & 3, lane = (i >> 2) & 63, ot = (i >> 8) & 7, sc = (i >> 11) & 7, kk = i >> 14;
    int o = ot * 16 + (lane & 15);
    int c = sc * 16 + ((lane >> 4) << 2) + j;
    wdef[i] = (_Float16)w_def[(o * 128 + c) * 9 + kk];
  }
  // woff A-frag (16x16x32): o = mt*16+(lane&15) (zero if >=72), c = ks*32+(lane>>4)*8+j
  for (int i = idx; i < 10240; i += stride) {
    int j = i & 7, lane = (i >> 3) & 63, t = i >> 9;
    int mt = t % 5, ks = t / 5;
    int o = mt * 16 + (lane & 15);
    int c = ks * 32 + ((lane >> 4) << 3) + j;
    woff[i] = (o < 72) ? (_Float16)w_off[o * 128 + c] : (_Float16)0.f;
  }
}

// ---------------- kernel 1: offset conv as f16 MFMA ----------------
// block = (b,h) row; stage x row as B-frags (K=128), 40 MFMA, pack half2 out.
__global__ __launch_bounds__(256) void offset_conv(
    const float* __restrict__ x, const _Float16* __restrict__ woff,
    const float* __restrict__ b_off, unsigned* __restrict__ offs2) {
  __shared__ uint4 bfr[4 * 8 * 64];  // [ks][nt][lane] 16B B-frags, 32 KB
  int tid = threadIdx.x, lane = tid & 63, wv = tid >> 6;
  int i = blockIdx.x;
  int L = (i & 7) * 64 + (i >> 3);   // XCD band swizzle
  int b = L >> 7, h = L & 127;

  int px = tid & 127;
  int octb = tid >> 7;
#pragma unroll
  for (int k2 = 0; k2 < 8; k2++) {
    int oct = octb + 2 * k2;         // 8-channel octet 0..15
    const float* xp = x + (((size_t)b * 128 + oct * 8) * 128 + h) * 128 + px;
    float v[8];
#pragma unroll
    for (int j = 0; j < 8; j++) v[j] = xp[(size_t)j * HW];
    uint4 q;
    q.x = pkrtz(v[0], v[1]); q.y = pkrtz(v[2], v[3]);
    q.z = pkrtz(v[4], v[5]); q.w = pkrtz(v[6], v[7]);
    int ks = oct >> 2, quad = oct & 3;
    bfr[(ks * 8 + (px >> 4)) * 64 + quad * 16 + (px & 15)] = q;
  }
  __syncthreads();

  floatx4 acc[5][2];
#pragma unroll
  for (int mt = 0; mt < 5; mt++) { acc[mt][0] = (floatx4)0.f; acc[mt][1] = (floatx4)0.f; }
  const h8* A = (const h8*)woff;
#pragma unroll
  for (int ks = 0; ks < 4; ks++) {
    h8 bv0 = *(const h8*)&bfr[(ks * 8 + 2 * wv) * 64 + lane];
    h8 bv1 = *(const h8*)&bfr[(ks * 8 + 2 * wv + 1) * 64 + lane];
#pragma unroll
    for (int mt = 0; mt < 5; mt++) {
      h8 av = A[(ks * 5 + mt) * 64 + lane];
      acc[mt][0] = __builtin_amdgcn_mfma_f32_16x16x32_f16(av, bv0, acc[mt][0], 0, 0, 0);
      acc[mt][1] = __builtin_amdgcn_mfma_f32_16x16x32_f16(av, bv1, acc[mt][1], 0, 0, 0);
    }
  }
  // epilogue: rows o = mt*16+quad*4+reg; pack (dy,dx) o-pairs as half2
  int quad = lane >> 4, col = lane & 15;
#pragma unroll
  for (int mt = 0; mt < 5; mt++) {
    if (mt == 4 && quad >= 2) continue;   // rows 72..79 are padding
    int o0 = mt * 16 + quad * 4;
    float4 bo = *(const float4*)(b_off + o0);
#pragma unroll
    for (int nn = 0; nn < 2; nn++) {
      floatx4 f = acc[mt][nn];
      int pp = (2 * wv + nn) * 16 + col;
      unsigned* dst = offs2 + ((size_t)b * 36 + (o0 >> 1)) * HW + h * 128 + pp;
      dst[0]  = pkrtz(f[0] + bo.x, f[1] + bo.y);
      dst[HW] = pkrtz(f[2] + bo.z, f[3] + bo.w);
    }
  }
}

// ---------------- kernel 2: deform conv, LDS-staged gather + MFMA ----------------
__global__ __launch_bounds__(256, 2) void deform_conv(
    const float* __restrict__ x, const _Float16* __restrict__ wdef,
    const unsigned* __restrict__ offs2, float* __restrict__ out) {
  __shared__ uint2 xs[4 * 7 * 128];      // staged x: [cq4][r7][px128] f16 quads, 28 KB
  __shared__ uint2 bfragB[2][512];       // B-frag double buffer, 8 KB
  __shared__ unsigned rec_a[1152];       // [kk9][px128] a0|a1<<16 (r*128+xb)
  __shared__ uint2 rec_w[1152];          // {pk(wy0,wy1), pk(wA,wB)}

  int tid = threadIdx.x, lane = tid & 63, wv = tid >> 6;
  int i = blockIdx.x;
  int L = (i & 7) * 64 + (i >> 3);       // XCD band swizzle
  int b = L >> 7, h = L & 127;
  int rlo = min(max(h - 3, 0), 121);     // staged rows rlo..rlo+6
  int px = tid & 127;
  int cqb = tid >> 7;

  floatx4 acc[2][8];
#pragma unroll
  for (int ot = 0; ot < 2; ot++)
#pragma unroll
    for (int nt = 0; nt < 8; nt++) acc[ot][nt] = (floatx4)0.f;

  int ph = 0;
  for (int sc = 0; sc < 8; sc++) {       // 16-channel sub-chunks
    // ---- stage 16ch x 7 rows of x -> xs (f16 channel-quads) ----
#pragma unroll
    for (int it = 0; it < 4; it++) {
      int u = tid + it * 256;
      if (u < 896) {
        int px4 = (u & 31) * 4, cq = (u >> 5) & 3, r = u >> 7;
        int gr = rlo + r;
        const float* xp = x + (((size_t)b * 128 + sc * 16 + cq * 4) * 128 + gr) * 128 + px4;
        float4 v0 = *(const float4*)xp;
        float4 v1 = *(const float4*)(xp + HW);
        float4 v2 = *(const float4*)(xp + 2 * HW);
        float4 v3 = *(const float4*)(xp + 3 * HW);
        uint2* dst = &xs[(cq * 7 + r) * 128 + px4];
        uint2 t;
        t.x = pkrtz(v0.x, v1.x); t.y = pkrtz(v2.x, v3.x); dst[0] = t;
        t.x = pkrtz(v0.y, v1.y); t.y = pkrtz(v2.y, v3.y); dst[1] = t;
        t.x = pkrtz(v0.z, v1.z); t.y = pkrtz(v2.z, v3.z); dst[2] = t;
        t.x = pkrtz(v0.w, v1.w); t.y = pkrtz(v2.w, v3.w); dst[3] = t;
      }
    }
    // ---- records for all 9 kk, group g = sc>>1 ----
    int g = sc >> 1;
#pragma unroll
    for (int it = 0; it < 5; it++) {
      int u = tid + it * 256;
      if (u < 1152) {
        int kk = u >> 7, p = u & 127;
        unsigned dd = offs2[((size_t)b * 36 + g * 9 + kk) * HW + h * 128 + p];
        h2 d = u2h2(dd);
        float dy = (float)d[0], dx = (float)d[1];
        float py = (float)h + (float)(kk / 3 - 1) + dy;
        float pxf = (float)p + (float)(kk % 3 - 1) + dx;
        float y0f = floorf(py), x0f = floorf(pxf);
        int y0 = (int)y0f, x0 = (int)x0f;
        float wy1 = py - y0f, wx1 = pxf - x0f;
        float wy0 = 1.f - wy1, wx0 = 1.f - wx1;
        int y1 = y0 + 1, x1 = x0 + 1;
        int xb = min(max(x0, 0), 126);
        float fx0 = (x0 >= 0 && x0 <= 127) ? 1.f : 0.f;
        float fx1 = (x1 >= 0 && x1 <= 127) ? 1.f : 0.f;
        float wA = (x0 == xb ? wx0 * fx0 : 0.f) + (x1 == xb ? wx1 * fx1 : 0.f);
        float wB = (x0 == xb + 1 ? wx0 * fx0 : 0.f) + (x1 == xb + 1 ? wx1 * fx1 : 0.f);
        float fy0 = (y0 >= 0 && y0 <= 127) ? 1.f : 0.f;
        float fy1 = (y1 >= 0 && y1 <= 127) ? 1.f : 0.f;
        int r0 = min(max(min(max(y0, 0), 127) - rlo, 0), 6);
        int r1 = min(max(min(max(y1, 0), 127) - rlo, 0), 6);
        rec_a[u] = (unsigned)(r0 * 128 + xb) | ((unsigned)(r1 * 128 + xb) << 16);
        uint2 t;
        t.x = pkrtz(wy0 * fy0, wy1 * fy1);
        t.y = pkrtz(wA, wB);
        rec_w[u] = t;
      }
    }
    __syncthreads();

    for (int kk = 0; kk < 9; kk++, ph++) {
      // ---- gather from LDS, packed f16 bilinear ----
      unsigned aw = rec_a[kk * 128 + px];
      uint2 rw = rec_w[kk * 128 + px];
      int a0 = aw & 0xffff, a1 = aw >> 16;
      unsigned lo0 = rw.x & 0xffffu, hi0 = rw.x >> 16;
      unsigned loA = rw.y & 0xffffu, hiA = rw.y >> 16;
      h2 wy0_2 = u2h2(lo0 | (lo0 << 16));
      h2 wy1_2 = u2h2(hi0 | (hi0 << 16));
      h2 wA_2 = u2h2(loA | (loA << 16));
      h2 wB_2 = u2h2(hiA | (hiA << 16));
      uint2* bb = bfragB[ph & 1];
#pragma unroll
      for (int k2 = 0; k2 < 2; k2++) {
        int cq = cqb + 2 * k2;
        const uint2* base = &xs[cq * 896];
        uint2 P = base[a0], Q = base[a0 + 1];
        uint2 R = base[a1], S = base[a1 + 1];
        h2 t0 = wA_2 * u2h2(P.x) + wB_2 * u2h2(Q.x);
        h2 t1 = wA_2 * u2h2(P.y) + wB_2 * u2h2(Q.y);
        h2 u0 = wy0_2 * t0 + wy1_2 * (wA_2 * u2h2(R.x) + wB_2 * u2h2(S.x));
        h2 u1 = wy0_2 * t1 + wy1_2 * (wA_2 * u2h2(R.y) + wB_2 * u2h2(S.y));
        uint2 t; t.x = h2u(u0); t.y = h2u(u1);
        bb[(px >> 4) * 64 + cq * 16 + (px & 15)] = t;
      }
      __syncthreads();
      // ---- MFMA K=16: wave wv -> o tiles {2wv, 2wv+1} ----
      const h4* A = (const h4*)wdef + (size_t)((kk * 8 + sc) * 8) * 64;
      h4 av0 = A[(2 * wv) * 64 + lane];
      h4 av1 = A[(2 * wv + 1) * 64 + lane];
      const uint2* bbr = bfragB[ph & 1];
#pragma unroll
      for (int nt = 0; nt < 8; nt++) {
        h4 bv = __builtin_bit_cast(h4, bbr[nt * 64 + lane]);
        acc[0][nt] = __builtin_amdgcn_mfma_f32_16x16x16f16(av0, bv, acc[0][nt], 0, 0, 0);
        acc[1][nt] = __builtin_amdgcn_mfma_f32_16x16x16f16(av1, bv, acc[1][nt], 0, 0, 0);
      }
    }
  }

  // ---- epilogue: C/D col=lane&15 (px), row=quad*4+reg (o); ReLU ----
  int quad = lane >> 4, col = lane & 15;
  float* ob = out + ((size_t)b * 128 + wv * 32) * HW + h * 128;
#pragma unroll
  for (int ot = 0; ot < 2; ot++)
#pragma unroll
    for (int nt = 0; nt < 8; nt++) {
      floatx4 f = acc[ot][nt];
      int pp = nt * 16 + col;
#pragma unroll
      for (int reg = 0; reg < 4; reg++) {
        int o = ot * 16 + quad * 4 + reg;
        ob[(size_t)o * HW + pp] = fmaxf(f[reg], 0.f);
      }
    }
}

extern "C" void kernel_launch(void* const* d_in, const int* in_sizes, int n_in,
                              void* d_out, int out_size, void* d_ws, size_t ws_size,
                              hipStream_t stream) {
  const float* x     = (const float*)d_in[0];
  const float* w_off = (const float*)d_in[1];
  const float* b_off = (const float*)d_in[2];
  const float* w_def = (const float*)d_in[3];
  float* out = (float*)d_out;

  _Float16* wdef = (_Float16*)d_ws;
  _Float16* woff = (_Float16*)((char*)d_ws + 294912);
  unsigned* offs2 = (unsigned*)((char*)d_ws + 315392);

  hipLaunchKernelGGL(prep_w, dim3(256), dim3(256), 0, stream, w_off, w_def, woff, wdef);
  hipLaunchKernelGGL(offset_conv, dim3(512), dim3(256), 0, stream, x, woff, b_off, offs2);
  hipLaunchKernelGGL(deform_conv, dim3(512), dim3(256), 0, stream, x, wdef, offs2, out);
}